// Round 1
// baseline (356.505 us; speedup 1.0000x reference)
//
#include <hip/hip_runtime.h>

typedef unsigned short u16;
typedef __attribute__((ext_vector_type(4))) float f32x4;
typedef __attribute__((ext_vector_type(8))) short bf16x8;

#define MFMA16(a,b,c) __builtin_amdgcn_mfma_f32_16x16x32_bf16((a),(b),(c),0,0,0)

__device__ inline u16 f2bf(float f){
  union { float f; unsigned u; } v; v.f = f;
  unsigned r = v.u + 0x7FFFu + ((v.u >> 16) & 1u);
  return (u16)(r >> 16);
}

__device__ inline void storeC(float* p, float v){ *p = v; }
__device__ inline void storeC(u16* p, float v){ *p = f2bf(v); }

typedef const __attribute__((address_space(1))) unsigned int* gas_ptr;
typedef __attribute__((address_space(3))) unsigned int* las_ptr;

__device__ inline void gload_lds16(const u16* g, u16* l){
  __builtin_amdgcn_global_load_lds((gas_ptr)(const void*)g, (las_ptr)(void*)l, 16, 0, 0);
}

// ---------------- fp32 -> bf16 convert (vectorized) ----------------
__global__ void k_cvt(const float* __restrict__ x, u16* __restrict__ y, int n4){
  int i = blockIdx.x*blockDim.x + threadIdx.x;
  if (i < n4){
    float4 v = ((const float4*)x)[i];
    ushort4 o;
    o.x = f2bf(v.x); o.y = f2bf(v.y); o.z = f2bf(v.z); o.w = f2bf(v.w);
    ((ushort4*)y)[i] = o;
  }
}

// ---------------- W (K x N) fp32 -> Wt (N x K) bf16 ----------------
__global__ void k_twb(const float* __restrict__ W, u16* __restrict__ Wt){
  __shared__ u16 t[32][33];
  int kb = blockIdx.x*32, nb = blockIdx.y*32;
  int tx = threadIdx.x, ty = threadIdx.y;
  #pragma unroll
  for (int i=0;i<32;i+=8)
    t[ty+i][tx] = f2bf(W[(size_t)(kb+ty+i)*1024 + nb+tx]);
  __syncthreads();
  #pragma unroll
  for (int i=0;i<32;i+=8)
    Wt[(size_t)(nb+ty+i)*1024 + kb+tx] = t[tx][ty+i];
}

// ---------------- V (B*T, D) bf16 -> VT (B,H,DH,T) bf16 ----------------
__global__ void k_tv(const u16* __restrict__ V, u16* __restrict__ VT){
  __shared__ u16 t[32][33];
  int tb = blockIdx.x*32;     // t tile
  int db = blockIdx.y*32;     // d tile within head (0 or 32)
  int bh = blockIdx.z;        // b*16+h
  int b = bh>>4, h = bh&15;
  int tx = threadIdx.x, ty = threadIdx.y;
  #pragma unroll
  for (int i=0;i<32;i+=8)
    t[ty+i][tx] = V[(size_t)(b*2048 + tb+ty+i)*1024 + h*64 + db+tx];
  __syncthreads();
  #pragma unroll
  for (int i=0;i<32;i+=8)
    VT[(size_t)(bh*64 + db+ty+i)*2048 + tb+tx] = t[tx][ty+i];
}

// ---------------- bf16 GEMM: C = A(MxK) * Bt(NxK)^T + bias ----------------
// 128x128 tile, BK=64, 256 threads (4 waves, 2x2 of 64x64)
template<typename OutT>
__global__ __launch_bounds__(256) void k_gemm(
    const u16* __restrict__ A, const u16* __restrict__ Bt,
    const float* __restrict__ bias, OutT* __restrict__ C,
    int M, int N, int K)
{
  __shared__ __attribute__((aligned(16))) u16 As[128*64];
  __shared__ __attribute__((aligned(16))) u16 Bs[128*64];
  const int tid  = threadIdx.x;
  const int wave = tid>>6, lane = tid&63;
  const int lo = lane&15, hi = lane>>4;
  const int row0 = blockIdx.x*128, col0 = blockIdx.y*128;
  const int wm = (wave>>1)*64, wn = (wave&1)*64;
  f32x4 acc[4][4];
  #pragma unroll
  for (int i=0;i<4;i++)
    #pragma unroll
    for (int j=0;j<4;j++) acc[i][j] = (f32x4){0.f,0.f,0.f,0.f};

  for (int k0=0; k0<K; k0+=64){
    #pragma unroll
    for (int r=0;r<4;r++){
      int c = r*256 + tid;               // 16B chunk id, 1024 chunks per tile
      gload_lds16(A  + (size_t)(row0 + (c>>3))*K + k0 + (c&7)*8, As + c*8);
      gload_lds16(Bt + (size_t)(col0 + (c>>3))*K + k0 + (c&7)*8, Bs + c*8);
    }
    __syncthreads();
    #pragma unroll
    for (int ks=0;ks<2;ks++){
      bf16x8 af[4], bfr[4];
      #pragma unroll
      for (int mf=0;mf<4;mf++)
        af[mf] = *(const bf16x8*)(As + (wm+mf*16+lo)*64 + ks*32 + hi*8);
      #pragma unroll
      for (int nf=0;nf<4;nf++)
        bfr[nf] = *(const bf16x8*)(Bs + (wn+nf*16+lo)*64 + ks*32 + hi*8);
      #pragma unroll
      for (int mf=0;mf<4;mf++)
        #pragma unroll
        for (int nf=0;nf<4;nf++)
          acc[mf][nf] = MFMA16(af[mf], bfr[nf], acc[mf][nf]);
    }
    __syncthreads();
  }
  #pragma unroll
  for (int mf=0;mf<4;mf++){
    #pragma unroll
    for (int nf=0;nf<4;nf++){
      int r0 = row0 + wm + mf*16 + hi*4;
      int c0 = col0 + wn + nf*16 + lo;
      float bb = bias[c0];
      #pragma unroll
      for (int r=0;r<4;r++)
        storeC(&C[(size_t)(r0+r)*N + c0], acc[mf][nf][r] + bb);
    }
  }
}

// ---------------- flash attention (causal) ----------------
// grid (T/64, B*H), 256 threads; wave w handles 16 q-rows.
__global__ __launch_bounds__(256) void k_attn(
    const u16* __restrict__ Q, const u16* __restrict__ Kp,
    const u16* __restrict__ VT, u16* __restrict__ O)
{
  const int T=2048, D=1024, DH=64;
  __shared__ __attribute__((aligned(16))) u16 Plds[4][16][64];
  const int qb = blockIdx.x;
  const int bh = blockIdx.y;
  const int b = bh>>4, h = bh&15;
  const int wave = threadIdx.x>>6, lane = threadIdx.x&63;
  const int lo = lane&15, hi = lane>>4;
  const int qrow0 = qb*64 + wave*16;
  const float NEG = -__builtin_inff();
  const float sc = 0.125f * 1.44269504f;  // 1/sqrt(64) * log2(e), exp2 domain

  const u16* Qb = Q + (size_t)(b*T + qrow0 + lo)*D + h*DH;
  bf16x8 qf0 = *(const bf16x8*)(Qb + hi*8);
  bf16x8 qf1 = *(const bf16x8*)(Qb + 32 + hi*8);

  f32x4 o[4];
  #pragma unroll
  for (int nf=0;nf<4;nf++) o[nf] = (f32x4){0.f,0.f,0.f,0.f};
  float m[4], l[4];
  #pragma unroll
  for (int r=0;r<4;r++){ m[r] = NEG; l[r] = 0.f; }

  for (int kb=0; kb<=qb; kb++){
    // ---- S = Q K^T (16x64 per wave) ----
    f32x4 s[4];
    #pragma unroll
    for (int nf=0;nf<4;nf++) s[nf] = (f32x4){0.f,0.f,0.f,0.f};
    const u16* Kb0 = Kp + (size_t)(b*T + kb*64 + lo)*D + h*DH;
    #pragma unroll
    for (int nf=0;nf<4;nf++){
      const u16* Kb = Kb0 + (size_t)(nf*16)*D;
      bf16x8 kf0 = *(const bf16x8*)(Kb + hi*8);
      bf16x8 kf1 = *(const bf16x8*)(Kb + 32 + hi*8);
      s[nf] = MFMA16(qf0, kf0, s[nf]);
      s[nf] = MFMA16(qf1, kf1, s[nf]);
    }
    // ---- scale + causal mask + row max ----
    const bool diag = (kb==qb);
    float ls[4][4];
    float pm[4] = {NEG,NEG,NEG,NEG};
    #pragma unroll
    for (int nf=0;nf<4;nf++){
      int col = kb*64 + nf*16 + lo;
      #pragma unroll
      for (int r=0;r<4;r++){
        int row = qrow0 + hi*4 + r;
        float v = s[nf][r]*sc;
        if (diag && col > row) v = NEG;
        ls[nf][r] = v;
        pm[r] = fmaxf(pm[r], v);
      }
    }
    #pragma unroll
    for (int mk=1; mk<16; mk<<=1)
      #pragma unroll
      for (int r=0;r<4;r++) pm[r] = fmaxf(pm[r], __shfl_xor(pm[r], mk));
    // ---- online rescale ----
    float alpha[4];
    #pragma unroll
    for (int r=0;r<4;r++){
      float mn = fmaxf(m[r], pm[r]);
      alpha[r] = __builtin_amdgcn_exp2f(m[r] - mn);
      m[r] = mn;
    }
    float rs[4] = {0.f,0.f,0.f,0.f};
    #pragma unroll
    for (int nf=0;nf<4;nf++)
      #pragma unroll
      for (int r=0;r<4;r++){
        float p = __builtin_amdgcn_exp2f(ls[nf][r] - m[r]);
        rs[r] += p;
        Plds[wave][hi*4+r][nf*16+lo] = f2bf(p);
      }
    #pragma unroll
    for (int mk=1; mk<16; mk<<=1)
      #pragma unroll
      for (int r=0;r<4;r++) rs[r] += __shfl_xor(rs[r], mk);
    #pragma unroll
    for (int r=0;r<4;r++) l[r] = l[r]*alpha[r] + rs[r];
    #pragma unroll
    for (int nf=0;nf<4;nf++)
      #pragma unroll
      for (int r=0;r<4;r++) o[nf][r] *= alpha[r];
    // ---- O += P V (P via per-wave LDS; same-wave, no barrier needed) ----
    bf16x8 pa0 = *(const bf16x8*)(&Plds[wave][lo][hi*8]);
    bf16x8 pa1 = *(const bf16x8*)(&Plds[wave][lo][32 + hi*8]);
    const u16* Vb0 = VT + (size_t)(bh*64 + lo)*T + kb*64;
    #pragma unroll
    for (int nf=0;nf<4;nf++){
      const u16* Vb = Vb0 + (size_t)(nf*16)*T;
      bf16x8 v0 = *(const bf16x8*)(Vb + hi*8);
      bf16x8 v1 = *(const bf16x8*)(Vb + 32 + hi*8);
      o[nf] = MFMA16(pa0, v0, o[nf]);
      o[nf] = MFMA16(pa1, v1, o[nf]);
    }
  }
  // ---- write O (bf16) ----
  #pragma unroll
  for (int nf=0;nf<4;nf++)
    #pragma unroll
    for (int r=0;r<4;r++){
      int row = qrow0 + hi*4 + r;
      O[(size_t)(b*T+row)*D + h*DH + nf*16 + lo] = f2bf(o[nf][r] / l[r]);
    }
}

extern "C" void kernel_launch(void* const* d_in, const int* in_sizes, int n_in,
                              void* d_out, int out_size, void* d_ws, size_t ws_size,
                              hipStream_t stream) {
  const int B=2, T=2048, D=1024;
  const int M = B*T;            // 4096
  const float* query = (const float*)d_in[0];
  const float* key   = (const float*)d_in[1];
  const float* value = (const float*)d_in[2];
  const float* Wq = (const float*)d_in[3];  const float* bq = (const float*)d_in[4];
  const float* Wk = (const float*)d_in[5];  const float* bk = (const float*)d_in[6];
  const float* Wv = (const float*)d_in[7];  const float* bv = (const float*)d_in[8];
  const float* Wo = (const float*)d_in[9];  const float* bo = (const float*)d_in[10];
  // d_in[11] = causal mask — known tril, applied analytically in k_attn.
  float* out = (float*)d_out;

  char* ws = (char*)d_ws;
  const size_t MB = 1024*1024;
  u16* xq  = (u16*)(ws + 0*MB);
  u16* xk  = (u16*)(ws + 8*MB);
  u16* xv  = (u16*)(ws + 16*MB);
  u16* WqT = (u16*)(ws + 24*MB);
  u16* WkT = (u16*)(ws + 26*MB);
  u16* WvT = (u16*)(ws + 28*MB);
  u16* WoT = (u16*)(ws + 30*MB);
  u16* Qp  = (u16*)(ws + 32*MB);
  u16* Kp  = (u16*)(ws + 40*MB);
  u16* Vp  = (u16*)(ws + 48*MB);
  u16* VTp = (u16*)(ws + 56*MB);
  u16* AO  = (u16*)(ws + 64*MB);

  // 1) fp32 -> bf16 activations
  int n4 = M*D/4;
  k_cvt<<<n4/256, 256, 0, stream>>>(query, xq, n4);
  k_cvt<<<n4/256, 256, 0, stream>>>(key,   xk, n4);
  k_cvt<<<n4/256, 256, 0, stream>>>(value, xv, n4);
  // 2) weight transposes (fp32 KxN -> bf16 NxK)
  dim3 tb(32,8);
  k_twb<<<dim3(32,32), tb, 0, stream>>>(Wq, WqT);
  k_twb<<<dim3(32,32), tb, 0, stream>>>(Wk, WkT);
  k_twb<<<dim3(32,32), tb, 0, stream>>>(Wv, WvT);
  k_twb<<<dim3(32,32), tb, 0, stream>>>(Wo, WoT);
  // 3) Q/K/V projections (bf16 out)
  dim3 gg(M/128, D/128);
  k_gemm<u16><<<gg, 256, 0, stream>>>(xq, WqT, bq, Qp, M, D, D);
  k_gemm<u16><<<gg, 256, 0, stream>>>(xk, WkT, bk, Kp, M, D, D);
  k_gemm<u16><<<gg, 256, 0, stream>>>(xv, WvT, bv, Vp, M, D, D);
  // 4) per-head V transpose for PV B-operand
  k_tv<<<dim3(T/32, 2, 32), tb, 0, stream>>>(Vp, VTp);
  // 5) causal flash attention
  k_attn<<<dim3(T/64, 32), 256, 0, stream>>>(Qp, Kp, VTp, AO);
  // 6) output projection (fp32 out + bias)
  k_gemm<float><<<gg, 256, 0, stream>>>(AO, WoT, bo, out, M, D, D);
}

// Round 2
// 197.191 us; speedup vs baseline: 1.8079x; 1.8079x over previous
//
#include <hip/hip_runtime.h>

typedef unsigned short u16;
typedef __attribute__((ext_vector_type(4))) float f32x4;
typedef __attribute__((ext_vector_type(8))) short bf16x8;

#define MFMA16(a,b,c) __builtin_amdgcn_mfma_f32_16x16x32_bf16((a),(b),(c),0,0,0)

__device__ inline u16 f2bf(float f){
  union { float f; unsigned u; } v; v.f = f;
  unsigned r = v.u + 0x7FFFu + ((v.u >> 16) & 1u);
  return (u16)(r >> 16);
}

__device__ inline void storeC(float* p, float v){ *p = v; }
__device__ inline void storeC(u16* p, float v){ *p = f2bf(v); }

typedef const __attribute__((address_space(1))) unsigned int* gas_ptr;
typedef __attribute__((address_space(3))) unsigned int* las_ptr;

__device__ inline void gload_lds16(const u16* g, u16* l){
  __builtin_amdgcn_global_load_lds((gas_ptr)(const void*)g, (las_ptr)(void*)l, 16, 0, 0);
}

// ---------------- fp32 -> bf16 convert (vectorized) ----------------
__global__ void k_cvt(const float* __restrict__ x, u16* __restrict__ y, int n4){
  int i = blockIdx.x*blockDim.x + threadIdx.x;
  if (i < n4){
    float4 v = ((const float4*)x)[i];
    ushort4 o;
    o.x = f2bf(v.x); o.y = f2bf(v.y); o.z = f2bf(v.z); o.w = f2bf(v.w);
    ((ushort4*)y)[i] = o;
  }
}

// ---------------- W (K x N) fp32 -> Wt (N x K) bf16 ----------------
__global__ void k_twb(const float* __restrict__ W, u16* __restrict__ Wt){
  __shared__ u16 t[32][33];
  int kb = blockIdx.x*32, nb = blockIdx.y*32;
  int tx = threadIdx.x, ty = threadIdx.y;
  #pragma unroll
  for (int i=0;i<32;i+=8)
    t[ty+i][tx] = f2bf(W[(size_t)(kb+ty+i)*1024 + nb+tx]);
  __syncthreads();
  #pragma unroll
  for (int i=0;i<32;i+=8)
    Wt[(size_t)(nb+ty+i)*1024 + kb+tx] = t[tx][ty+i];
}

// ---------------- V (B*T, D) bf16 -> VT (B,H,DH,T) bf16 ----------------
__global__ void k_tv(const u16* __restrict__ V, u16* __restrict__ VT){
  __shared__ u16 t[32][33];
  int tb = blockIdx.x*32;
  int db = blockIdx.y*32;
  int bh = blockIdx.z;
  int b = bh>>4, h = bh&15;
  int tx = threadIdx.x, ty = threadIdx.y;
  #pragma unroll
  for (int i=0;i<32;i+=8)
    t[ty+i][tx] = V[(size_t)(b*2048 + tb+ty+i)*1024 + h*64 + db+tx];
  __syncthreads();
  #pragma unroll
  for (int i=0;i<32;i+=8)
    VT[(size_t)(bh*64 + db+ty+i)*2048 + tb+tx] = t[tx][ty+i];
}

// ---------------- bf16 GEMM: C = A(MxK) * Bt(NxK)^T + bias ----------------
template<typename OutT>
__global__ __launch_bounds__(256) void k_gemm(
    const u16* __restrict__ A, const u16* __restrict__ Bt,
    const float* __restrict__ bias, OutT* __restrict__ C,
    int M, int N, int K)
{
  __shared__ __attribute__((aligned(16))) u16 As[128*64];
  __shared__ __attribute__((aligned(16))) u16 Bs[128*64];
  const int tid  = threadIdx.x;
  const int wave = tid>>6, lane = tid&63;
  const int lo = lane&15, hi = lane>>4;
  const int row0 = blockIdx.x*128, col0 = blockIdx.y*128;
  const int wm = (wave>>1)*64, wn = (wave&1)*64;
  f32x4 acc[4][4];
  #pragma unroll
  for (int i=0;i<4;i++)
    #pragma unroll
    for (int j=0;j<4;j++) acc[i][j] = (f32x4){0.f,0.f,0.f,0.f};

  for (int k0=0; k0<K; k0+=64){
    #pragma unroll
    for (int r=0;r<4;r++){
      int c = r*256 + tid;
      gload_lds16(A  + (size_t)(row0 + (c>>3))*K + k0 + (c&7)*8, As + c*8);
      gload_lds16(Bt + (size_t)(col0 + (c>>3))*K + k0 + (c&7)*8, Bs + c*8);
    }
    __syncthreads();
    #pragma unroll
    for (int ks=0;ks<2;ks++){
      bf16x8 af[4], bfr[4];
      #pragma unroll
      for (int mf=0;mf<4;mf++)
        af[mf] = *(const bf16x8*)(As + (wm+mf*16+lo)*64 + ks*32 + hi*8);
      #pragma unroll
      for (int nf=0;nf<4;nf++)
        bfr[nf] = *(const bf16x8*)(Bs + (wn+nf*16+lo)*64 + ks*32 + hi*8);
      #pragma unroll
      for (int mf=0;mf<4;mf++)
        #pragma unroll
        for (int nf=0;nf<4;nf++)
          acc[mf][nf] = MFMA16(af[mf], bfr[nf], acc[mf][nf]);
    }
    __syncthreads();
  }
  #pragma unroll
  for (int mf=0;mf<4;mf++){
    #pragma unroll
    for (int nf=0;nf<4;nf++){
      int r0 = row0 + wm + mf*16 + hi*4;
      int c0 = col0 + wn + nf*16 + lo;
      float bb = bias[c0];
      #pragma unroll
      for (int r=0;r<4;r++)
        storeC(&C[(size_t)(r0+r)*N + c0], acc[mf][nf][r] + bb);
    }
  }
}

// ---------------- flash attention (causal), v2 ----------------
// grid (16, B*H): block x handles q-tiles x and 31-x (balanced: 33 kv-tiles).
// 256 threads (4 waves x 16 q-rows). K/V tiles staged in LDS, double-buffered,
// XOR-swizzled (linear LDS dest + pre-swizzled global source, rule #21).
__global__ __launch_bounds__(256) void k_attn(
    const u16* __restrict__ Q, const u16* __restrict__ Kp,
    const u16* __restrict__ VT, u16* __restrict__ O)
{
  const int T=2048, D=1024, NT=32;
  __shared__ __attribute__((aligned(16))) u16 Ks[2][64*64];
  __shared__ __attribute__((aligned(16))) u16 Vs[2][64*64];
  __shared__ __attribute__((aligned(16))) u16 Plds[4][16*64];
  const int bh = blockIdx.y;
  const int b = bh>>4, h = bh&15;
  const int tid = threadIdx.x;
  const int wave = tid>>6, lane = tid&63;
  const int lo = lane&15, hi = lane>>4;
  const float NEG = -__builtin_inff();
  const float sc = 0.125f * 1.44269504f;  // 1/sqrt(64) * log2(e)

  // swizzled fragment chunk offsets (u16 units): chunk j in row r lives at
  // LDS idx r*64 + ((j ^ (r&7))*8); for frag reads r&7 == lo&7, j = ks*4+hi.
  const int cof0 = ((hi    ) ^ (lo&7))*8;   // ks=0
  const int cof1 = ((hi + 4) ^ (lo&7))*8;   // ks=1

  // staging: thread handles 16B chunks c0=tid, c1=256+tid (of 512 per tile);
  // LDS dest linear (c*16B); global source column pre-swizzled.
  const int c0 = tid, c1 = 256 + tid;
  const int sr0 = c0>>3, sj0 = (c0&7)^(sr0&7);
  const int sr1 = c1>>3, sj1 = (c1&7)^(sr1&7);
  const u16* Kbase = Kp + (size_t)(b*T)*D + h*64;
  const u16* Vbase = VT + (size_t)(bh*64)*T;
  const size_t kOff0 = (size_t)sr0*D + sj0*8, kOff1 = (size_t)sr1*D + sj1*8;
  const size_t vOff0 = (size_t)sr0*T + sj0*8, vOff1 = (size_t)sr1*T + sj1*8;

  for (int half=0; half<2; half++){
    const int qb = half ? (NT-1-(int)blockIdx.x) : (int)blockIdx.x;
    const int qrow0 = qb*64 + wave*16;
    const u16* Qb = Q + (size_t)(b*T + qrow0 + lo)*D + h*64;
    bf16x8 qf0 = *(const bf16x8*)(Qb + hi*8);
    bf16x8 qf1 = *(const bf16x8*)(Qb + 32 + hi*8);

    f32x4 o[4];
    #pragma unroll
    for (int nf=0;nf<4;nf++) o[nf] = (f32x4){0.f,0.f,0.f,0.f};
    float m[4], l[4];
    #pragma unroll
    for (int r=0;r<4;r++){ m[r] = NEG; l[r] = 0.f; }

    // prologue: stage kb=0 into buf 0
    gload_lds16(Kbase + kOff0, &Ks[0][c0*8]);
    gload_lds16(Kbase + kOff1, &Ks[0][c1*8]);
    gload_lds16(Vbase + vOff0, &Vs[0][c0*8]);
    gload_lds16(Vbase + vOff1, &Vs[0][c1*8]);
    __syncthreads();

    int cur = 0;
    for (int kb=0; kb<=qb; kb++){
      // issue next-tile stage before compute (T3 2-phase)
      if (kb < qb){
        const u16* Kt = Kbase + (size_t)(kb+1)*64*D;
        const u16* Vt = Vbase + (kb+1)*64;
        gload_lds16(Kt + kOff0, &Ks[cur^1][c0*8]);
        gload_lds16(Kt + kOff1, &Ks[cur^1][c1*8]);
        gload_lds16(Vt + vOff0, &Vs[cur^1][c0*8]);
        gload_lds16(Vt + vOff1, &Vs[cur^1][c1*8]);
      }
      const u16* Kl = Ks[cur];
      const u16* Vl = Vs[cur];
      // ---- S = Q K^T ----
      f32x4 s[4];
      #pragma unroll
      for (int nf=0;nf<4;nf++){
        int row = nf*16 + lo;
        bf16x8 kf0 = *(const bf16x8*)(Kl + row*64 + cof0);
        bf16x8 kf1 = *(const bf16x8*)(Kl + row*64 + cof1);
        f32x4 z = (f32x4){0.f,0.f,0.f,0.f};
        z = MFMA16(qf0, kf0, z);
        s[nf] = MFMA16(qf1, kf1, z);
      }
      // ---- scale + causal mask + row max ----
      const bool diag = (kb==qb);
      float ls[4][4];
      float pm[4] = {NEG,NEG,NEG,NEG};
      #pragma unroll
      for (int nf=0;nf<4;nf++){
        int col = kb*64 + nf*16 + lo;
        #pragma unroll
        for (int r=0;r<4;r++){
          int row = qrow0 + hi*4 + r;
          float v = s[nf][r]*sc;
          if (diag && col > row) v = NEG;
          ls[nf][r] = v;
          pm[r] = fmaxf(pm[r], v);
        }
      }
      #pragma unroll
      for (int mk=1; mk<16; mk<<=1)
        #pragma unroll
        for (int r=0;r<4;r++) pm[r] = fmaxf(pm[r], __shfl_xor(pm[r], mk));
      // ---- online rescale ----
      float alpha[4];
      #pragma unroll
      for (int r=0;r<4;r++){
        float mn = fmaxf(m[r], pm[r]);
        alpha[r] = __builtin_amdgcn_exp2f(m[r] - mn);
        m[r] = mn;
      }
      float rs[4] = {0.f,0.f,0.f,0.f};
      #pragma unroll
      for (int nf=0;nf<4;nf++)
        #pragma unroll
        for (int r=0;r<4;r++){
          float p = __builtin_amdgcn_exp2f(ls[nf][r] - m[r]);
          rs[r] += p;
          int prow = hi*4+r, pcol = nf*16+lo;
          Plds[wave][prow*64 + (pcol ^ ((prow&7)<<3))] = f2bf(p);
        }
      #pragma unroll
      for (int mk=1; mk<16; mk<<=1)
        #pragma unroll
        for (int r=0;r<4;r++) rs[r] += __shfl_xor(rs[r], mk);
      #pragma unroll
      for (int r=0;r<4;r++) l[r] = l[r]*alpha[r] + rs[r];
      #pragma unroll
      for (int nf=0;nf<4;nf++)
        #pragma unroll
        for (int r=0;r<4;r++) o[nf][r] *= alpha[r];
      // ---- O += P V ----
      bf16x8 pa0 = *(const bf16x8*)(&Plds[wave][lo*64 + cof0]);
      bf16x8 pa1 = *(const bf16x8*)(&Plds[wave][lo*64 + cof1]);
      #pragma unroll
      for (int nf=0;nf<4;nf++){
        int row = nf*16 + lo;
        bf16x8 v0 = *(const bf16x8*)(Vl + row*64 + cof0);
        bf16x8 v1 = *(const bf16x8*)(Vl + row*64 + cof1);
        o[nf] = MFMA16(pa0, v0, o[nf]);
        o[nf] = MFMA16(pa1, v1, o[nf]);
      }
      __syncthreads();
      cur ^= 1;
    }
    // ---- write O (bf16) ----
    #pragma unroll
    for (int nf=0;nf<4;nf++)
      #pragma unroll
      for (int r=0;r<4;r++){
        int row = qrow0 + hi*4 + r;
        O[(size_t)(b*T+row)*D + h*64 + nf*16 + lo] = f2bf(o[nf][r] / l[r]);
      }
  }
}

extern "C" void kernel_launch(void* const* d_in, const int* in_sizes, int n_in,
                              void* d_out, int out_size, void* d_ws, size_t ws_size,
                              hipStream_t stream) {
  const int B=2, T=2048, D=1024;
  const int M = B*T;
  const float* query = (const float*)d_in[0];
  const float* key   = (const float*)d_in[1];
  const float* value = (const float*)d_in[2];
  const float* Wq = (const float*)d_in[3];  const float* bq = (const float*)d_in[4];
  const float* Wk = (const float*)d_in[5];  const float* bk = (const float*)d_in[6];
  const float* Wv = (const float*)d_in[7];  const float* bv = (const float*)d_in[8];
  const float* Wo = (const float*)d_in[9];  const float* bo = (const float*)d_in[10];
  float* out = (float*)d_out;

  char* ws = (char*)d_ws;
  const size_t MB = 1024*1024;
  u16* xq  = (u16*)(ws + 0*MB);
  u16* xk  = (u16*)(ws + 8*MB);
  u16* xv  = (u16*)(ws + 16*MB);
  u16* WqT = (u16*)(ws + 24*MB);
  u16* WkT = (u16*)(ws + 26*MB);
  u16* WvT = (u16*)(ws + 28*MB);
  u16* WoT = (u16*)(ws + 30*MB);
  u16* Qp  = (u16*)(ws + 32*MB);
  u16* Kp  = (u16*)(ws + 40*MB);
  u16* Vp  = (u16*)(ws + 48*MB);
  u16* VTp = (u16*)(ws + 56*MB);
  u16* AO  = (u16*)(ws + 64*MB);

  int n4 = M*D/4;
  k_cvt<<<n4/256, 256, 0, stream>>>(query, xq, n4);
  k_cvt<<<n4/256, 256, 0, stream>>>(key,   xk, n4);
  k_cvt<<<n4/256, 256, 0, stream>>>(value, xv, n4);
  dim3 tb(32,8);
  k_twb<<<dim3(32,32), tb, 0, stream>>>(Wq, WqT);
  k_twb<<<dim3(32,32), tb, 0, stream>>>(Wk, WkT);
  k_twb<<<dim3(32,32), tb, 0, stream>>>(Wv, WvT);
  k_twb<<<dim3(32,32), tb, 0, stream>>>(Wo, WoT);
  dim3 gg(M/128, D/128);
  k_gemm<u16><<<gg, 256, 0, stream>>>(xq, WqT, bq, Qp, M, D, D);
  k_gemm<u16><<<gg, 256, 0, stream>>>(xk, WkT, bk, Kp, M, D, D);
  k_gemm<u16><<<gg, 256, 0, stream>>>(xv, WvT, bv, Vp, M, D, D);
  k_tv<<<dim3(T/32, 2, 32), tb, 0, stream>>>(Vp, VTp);
  k_attn<<<dim3(16, 32), 256, 0, stream>>>(Qp, Kp, VTp, AO);
  k_gemm<float><<<gg, 256, 0, stream>>>(AO, WoT, bo, out, M, D, D);
}

// Round 3
// 141.593 us; speedup vs baseline: 2.5178x; 1.3927x over previous
//
#include <hip/hip_runtime.h>

typedef unsigned short u16;
typedef __attribute__((ext_vector_type(4))) float f32x4;
typedef __attribute__((ext_vector_type(8))) short bf16x8;

#define MFMA16(a,b,c) __builtin_amdgcn_mfma_f32_16x16x32_bf16((a),(b),(c),0,0,0)

__device__ inline u16 f2bf(float f){
  union { float f; unsigned u; } v; v.f = f;
  unsigned r = v.u + 0x7FFFu + ((v.u >> 16) & 1u);
  return (u16)(r >> 16);
}
__device__ inline void storeC(float* p, float v){ *p = v; }
__device__ inline void storeC(u16* p, float v){ *p = f2bf(v); }

typedef const __attribute__((address_space(1))) unsigned int* gas_ptr;
typedef __attribute__((address_space(3))) unsigned int* las_ptr;
__device__ inline void gload_lds16(const u16* g, u16* l){
  __builtin_amdgcn_global_load_lds((gas_ptr)(const void*)g, (las_ptr)(void*)l, 16, 0, 0);
}

// DPP rotate within 16-lane row: lane i <- lane (i+N)%16. VALU-rate cross-lane.
template<int N>
__device__ inline float rorf(float v){
  union { float f; int i; } a, b; a.f = v;
  b.i = __builtin_amdgcn_update_dpp(a.i, a.i, 0x120|N, 0xF, 0xF, false);
  return b.f;
}
__device__ inline float redMax16(float v){
  v = fmaxf(v, rorf<8>(v)); v = fmaxf(v, rorf<4>(v));
  v = fmaxf(v, rorf<2>(v)); v = fmaxf(v, rorf<1>(v));
  return v;
}
__device__ inline float redSum16(float v){
  v += rorf<8>(v); v += rorf<4>(v); v += rorf<2>(v); v += rorf<1>(v);
  return v;
}

// ---------------- fp32 -> bf16 convert, 3 tensors in one launch ----------------
struct CvtArgs { const float* x[3]; u16* y[3]; };
__global__ void k_cvt3(CvtArgs a, int n4){
  const float* x = a.x[blockIdx.y];
  u16* y = a.y[blockIdx.y];
  int i = blockIdx.x*blockDim.x + threadIdx.x;
  if (i < n4){
    float4 v = ((const float4*)x)[i];
    ushort4 o;
    o.x = f2bf(v.x); o.y = f2bf(v.y); o.z = f2bf(v.z); o.w = f2bf(v.w);
    ((ushort4*)y)[i] = o;
  }
}

// ---------------- W (K x N) fp32 -> Wt (N x K) bf16, 4 weights ----------------
struct TwbArgs { const float* W[4]; u16* Wt[4]; };
__global__ void k_twb4(TwbArgs a){
  __shared__ u16 t[32][33];
  const float* W = a.W[blockIdx.z];
  u16* Wt = a.Wt[blockIdx.z];
  int kb = blockIdx.x*32, nb = blockIdx.y*32;
  int tx = threadIdx.x, ty = threadIdx.y;
  #pragma unroll
  for (int i=0;i<32;i+=8)
    t[ty+i][tx] = f2bf(W[(size_t)(kb+ty+i)*1024 + nb+tx]);
  __syncthreads();
  #pragma unroll
  for (int i=0;i<32;i+=8)
    Wt[(size_t)(nb+ty+i)*1024 + kb+tx] = t[tx][ty+i];
}

// ---------------- V (B*T, D) bf16 -> VT (B,H,DH,T) bf16 ----------------
__global__ void k_tv(const u16* __restrict__ V, u16* __restrict__ VT){
  __shared__ u16 t[32][33];
  int tb = blockIdx.x*32;
  int db = blockIdx.y*32;
  int bh = blockIdx.z;
  int b = bh>>4, h = bh&15;
  int tx = threadIdx.x, ty = threadIdx.y;
  #pragma unroll
  for (int i=0;i<32;i+=8)
    t[ty+i][tx] = V[(size_t)(b*2048 + tb+ty+i)*1024 + h*64 + db+tx];
  __syncthreads();
  #pragma unroll
  for (int i=0;i<32;i+=8)
    VT[(size_t)(bh*64 + db+ty+i)*2048 + tb+tx] = t[tx][ty+i];
}

// ---------------- bf16 GEMM body: C = A(4096xK) * Bt(NxK)^T + bias ----------------
// 128x128 tile, BK=64, 256 threads (4 waves, 2x2 of 64x64)
template<typename OutT>
__device__ inline void gemm_body(const u16* __restrict__ A, const u16* __restrict__ Bt,
                                 const float* __restrict__ bias, OutT* __restrict__ C,
                                 int bx, int by){
  const int N=1024, K=1024;
  __shared__ __attribute__((aligned(16))) u16 As[128*64];
  __shared__ __attribute__((aligned(16))) u16 Bs[128*64];
  const int tid  = threadIdx.x;
  const int wave = tid>>6, lane = tid&63;
  const int lo = lane&15, hi = lane>>4;
  const int row0 = bx*128, col0 = by*128;
  const int wm = (wave>>1)*64, wn = (wave&1)*64;
  f32x4 acc[4][4];
  #pragma unroll
  for (int i=0;i<4;i++)
    #pragma unroll
    for (int j=0;j<4;j++) acc[i][j] = (f32x4){0.f,0.f,0.f,0.f};

  for (int k0=0; k0<K; k0+=64){
    #pragma unroll
    for (int r=0;r<4;r++){
      int c = r*256 + tid;
      gload_lds16(A  + (size_t)(row0 + (c>>3))*K + k0 + (c&7)*8, As + c*8);
      gload_lds16(Bt + (size_t)(col0 + (c>>3))*K + k0 + (c&7)*8, Bs + c*8);
    }
    __syncthreads();
    __builtin_amdgcn_s_setprio(1);
    #pragma unroll
    for (int ks=0;ks<2;ks++){
      bf16x8 af[4], bfr[4];
      #pragma unroll
      for (int mf=0;mf<4;mf++)
        af[mf] = *(const bf16x8*)(As + (wm+mf*16+lo)*64 + ks*32 + hi*8);
      #pragma unroll
      for (int nf=0;nf<4;nf++)
        bfr[nf] = *(const bf16x8*)(Bs + (wn+nf*16+lo)*64 + ks*32 + hi*8);
      #pragma unroll
      for (int mf=0;mf<4;mf++)
        #pragma unroll
        for (int nf=0;nf<4;nf++)
          acc[mf][nf] = MFMA16(af[mf], bfr[nf], acc[mf][nf]);
    }
    __builtin_amdgcn_s_setprio(0);
    __syncthreads();
  }
  #pragma unroll
  for (int mf=0;mf<4;mf++){
    #pragma unroll
    for (int nf=0;nf<4;nf++){
      int r0 = row0 + wm + mf*16 + hi*4;
      int c0 = col0 + wn + nf*16 + lo;
      float bb = bias[c0];
      #pragma unroll
      for (int r=0;r<4;r++)
        storeC(&C[(size_t)(r0+r)*N + c0], acc[mf][nf][r] + bb);
    }
  }
}

// QKV projections: one launch, grid (32,8,3), XCD-swizzled (768 = 8*96)
struct GemmArgs3 { const u16* A[3]; const u16* Bt[3]; const float* bias[3]; u16* C[3]; };
__global__ __launch_bounds__(256) void k_gemm3(GemmArgs3 g){
  int flat = blockIdx.x + (blockIdx.y<<5) + (blockIdx.z<<8);
  int swz = (flat&7)*96 + (flat>>3);
  int by = swz & 7, bx = (swz>>3) & 31, bz = swz >> 8;
  gemm_body<u16>(g.A[bz], g.Bt[bz], g.bias[bz], g.C[bz], bx, by);
}
// O projection (fp32 out), grid (32,8), XCD-swizzled (256 = 8*32)
__global__ __launch_bounds__(256) void k_gemmO(const u16* __restrict__ A, const u16* __restrict__ Bt,
                                               const float* __restrict__ bias, float* __restrict__ C){
  int flat = blockIdx.x + (blockIdx.y<<5);
  int swz = (flat&7)*32 + (flat>>3);
  int by = swz & 7, bx = swz >> 3;
  gemm_body<float>(A, Bt, bias, C, bx, by);
}

// ---------------- flash attention (causal), v3 ----------------
// grid (16, 32) XCD-swizzled; block handles q-tiles x and 31-x (33 kv-tiles).
// 256 threads (4 waves x 16 q-rows). K/V staged in LDS, double-buffered, swizzled.
// DPP rotate-reduce softmax, defer-rescale (T13), setprio (T5).
__global__ __launch_bounds__(256) void k_attn(
    const u16* __restrict__ Q, const u16* __restrict__ Kp,
    const u16* __restrict__ VT, u16* __restrict__ O)
{
  const int T=2048, D=1024, NT=32;
  __shared__ __attribute__((aligned(16))) u16 Ks[2][64*64];
  __shared__ __attribute__((aligned(16))) u16 Vs[2][64*64];
  __shared__ __attribute__((aligned(16))) u16 Plds[4][16*64];
  // XCD swizzle: 512 wgs, 64 per XCD -> all 16 q-blocks of a bh-group + its pair
  // land on the same XCD (K/V working set 4 bh x 512KB = 2MB < 4MB L2).
  int flat = blockIdx.x + (blockIdx.y<<4);
  int swz = (flat&7)*64 + (flat>>3);
  const int xb = swz & 15;
  const int bh = swz >> 4;
  const int b = bh>>4, h = bh&15;
  const int tid = threadIdx.x;
  const int wave = tid>>6, lane = tid&63;
  const int lo = lane&15, hi = lane>>4;
  const float NEG = -__builtin_inff();
  const float sc = 0.125f * 1.44269504f;  // 1/sqrt(64) * log2(e)

  const int cof0 = ((hi    ) ^ (lo&7))*8;
  const int cof1 = ((hi + 4) ^ (lo&7))*8;

  const int c0 = tid, c1 = 256 + tid;
  const int sr0 = c0>>3, sj0 = (c0&7)^(sr0&7);
  const int sr1 = c1>>3, sj1 = (c1&7)^(sr1&7);
  const u16* Kbase = Kp + (size_t)(b*T)*D + h*64;
  const u16* Vbase = VT + (size_t)(bh*64)*T;
  const size_t kOff0 = (size_t)sr0*D + sj0*8, kOff1 = (size_t)sr1*D + sj1*8;
  const size_t vOff0 = (size_t)sr0*T + sj0*8, vOff1 = (size_t)sr1*T + sj1*8;

  for (int half=0; half<2; half++){
    const int qb = half ? (NT-1-xb) : xb;
    const int qrow0 = qb*64 + wave*16;
    const u16* Qb = Q + (size_t)(b*T + qrow0 + lo)*D + h*64;
    bf16x8 qf0 = *(const bf16x8*)(Qb + hi*8);
    bf16x8 qf1 = *(const bf16x8*)(Qb + 32 + hi*8);

    f32x4 o[4];
    #pragma unroll
    for (int nf=0;nf<4;nf++) o[nf] = (f32x4){0.f,0.f,0.f,0.f};
    float m[4], l[4];
    #pragma unroll
    for (int r=0;r<4;r++){ m[r] = NEG; l[r] = 0.f; }

    gload_lds16(Kbase + kOff0, &Ks[0][c0*8]);
    gload_lds16(Kbase + kOff1, &Ks[0][c1*8]);
    gload_lds16(Vbase + vOff0, &Vs[0][c0*8]);
    gload_lds16(Vbase + vOff1, &Vs[0][c1*8]);
    __syncthreads();

    int cur = 0;
    for (int kb=0; kb<=qb; kb++){
      if (kb < qb){
        const u16* Kt = Kbase + (size_t)(kb+1)*64*D;
        const u16* Vt = Vbase + (kb+1)*64;
        gload_lds16(Kt + kOff0, &Ks[cur^1][c0*8]);
        gload_lds16(Kt + kOff1, &Ks[cur^1][c1*8]);
        gload_lds16(Vt + vOff0, &Vs[cur^1][c0*8]);
        gload_lds16(Vt + vOff1, &Vs[cur^1][c1*8]);
      }
      const u16* Kl = Ks[cur];
      const u16* Vl = Vs[cur];
      // ---- S = Q K^T ----
      f32x4 s[4];
      __builtin_amdgcn_s_setprio(1);
      #pragma unroll
      for (int nf=0;nf<4;nf++){
        int row = nf*16 + lo;
        bf16x8 kf0 = *(const bf16x8*)(Kl + row*64 + cof0);
        bf16x8 kf1 = *(const bf16x8*)(Kl + row*64 + cof1);
        f32x4 z = (f32x4){0.f,0.f,0.f,0.f};
        z = MFMA16(qf0, kf0, z);
        s[nf] = MFMA16(qf1, kf1, z);
      }
      __builtin_amdgcn_s_setprio(0);
      // ---- scale (+ causal mask only on diag tile) + row max ----
      float ls[4][4];
      float pm[4] = {NEG,NEG,NEG,NEG};
      if (kb == qb){
        #pragma unroll
        for (int nf=0;nf<4;nf++){
          int col = kb*64 + nf*16 + lo;
          #pragma unroll
          for (int r=0;r<4;r++){
            int row = qrow0 + hi*4 + r;
            float v = s[nf][r]*sc;
            if (col > row) v = NEG;
            ls[nf][r] = v;
            pm[r] = fmaxf(pm[r], v);
          }
        }
      } else {
        #pragma unroll
        for (int nf=0;nf<4;nf++)
          #pragma unroll
          for (int r=0;r<4;r++){
            float v = s[nf][r]*sc;
            ls[nf][r] = v;
            pm[r] = fmaxf(pm[r], v);
          }
      }
      #pragma unroll
      for (int r=0;r<4;r++) pm[r] = redMax16(pm[r]);
      // ---- defer-rescale (T13): skip o/l rescale when max growth <= 8 ----
      bool small = true;
      #pragma unroll
      for (int r=0;r<4;r++) small = small && (pm[r] <= m[r] + 8.f);
      const bool resc = !__all(small);
      float alpha[4];
      if (resc){
        #pragma unroll
        for (int r=0;r<4;r++){
          float mn = fmaxf(m[r], pm[r]);
          alpha[r] = __builtin_amdgcn_exp2f(m[r] - mn);
          m[r] = mn;
        }
      }
      float rs[4] = {0.f,0.f,0.f,0.f};
      #pragma unroll
      for (int nf=0;nf<4;nf++)
        #pragma unroll
        for (int r=0;r<4;r++){
          float p = __builtin_amdgcn_exp2f(ls[nf][r] - m[r]);
          rs[r] += p;
          int prow = hi*4+r, pcol = nf*16+lo;
          Plds[wave][prow*64 + (pcol ^ ((prow&7)<<3))] = f2bf(p);
        }
      #pragma unroll
      for (int r=0;r<4;r++) rs[r] = redSum16(rs[r]);
      if (resc){
        #pragma unroll
        for (int r=0;r<4;r++) l[r] = l[r]*alpha[r] + rs[r];
        #pragma unroll
        for (int nf=0;nf<4;nf++)
          #pragma unroll
          for (int r=0;r<4;r++) o[nf][r] *= alpha[r];
      } else {
        #pragma unroll
        for (int r=0;r<4;r++) l[r] += rs[r];
      }
      // ---- O += P V ----
      bf16x8 pa0 = *(const bf16x8*)(&Plds[wave][lo*64 + cof0]);
      bf16x8 pa1 = *(const bf16x8*)(&Plds[wave][lo*64 + cof1]);
      __builtin_amdgcn_s_setprio(1);
      #pragma unroll
      for (int nf=0;nf<4;nf++){
        int row = nf*16 + lo;
        bf16x8 v0 = *(const bf16x8*)(Vl + row*64 + cof0);
        bf16x8 v1 = *(const bf16x8*)(Vl + row*64 + cof1);
        o[nf] = MFMA16(pa0, v0, o[nf]);
        o[nf] = MFMA16(pa1, v1, o[nf]);
      }
      __builtin_amdgcn_s_setprio(0);
      __syncthreads();
      cur ^= 1;
    }
    // ---- write O (bf16) ----
    #pragma unroll
    for (int nf=0;nf<4;nf++)
      #pragma unroll
      for (int r=0;r<4;r++){
        int row = qrow0 + hi*4 + r;
        O[(size_t)(b*T+row)*D + h*64 + nf*16 + lo] = f2bf(o[nf][r] / l[r]);
      }
  }
}

extern "C" void kernel_launch(void* const* d_in, const int* in_sizes, int n_in,
                              void* d_out, int out_size, void* d_ws, size_t ws_size,
                              hipStream_t stream) {
  const int B=2, T=2048, D=1024;
  const int M = B*T;
  const float* query = (const float*)d_in[0];
  const float* key   = (const float*)d_in[1];
  const float* value = (const float*)d_in[2];
  const float* Wq = (const float*)d_in[3];  const float* bq = (const float*)d_in[4];
  const float* Wk = (const float*)d_in[5];  const float* bk = (const float*)d_in[6];
  const float* Wv = (const float*)d_in[7];  const float* bv = (const float*)d_in[8];
  const float* Wo = (const float*)d_in[9];  const float* bo = (const float*)d_in[10];
  float* out = (float*)d_out;

  char* ws = (char*)d_ws;
  const size_t MB = 1024*1024;
  u16* xq  = (u16*)(ws + 0*MB);
  u16* xk  = (u16*)(ws + 8*MB);
  u16* xv  = (u16*)(ws + 16*MB);
  u16* WqT = (u16*)(ws + 24*MB);
  u16* WkT = (u16*)(ws + 26*MB);
  u16* WvT = (u16*)(ws + 28*MB);
  u16* WoT = (u16*)(ws + 30*MB);
  u16* Qp  = (u16*)(ws + 32*MB);
  u16* Kp  = (u16*)(ws + 40*MB);
  u16* Vp  = (u16*)(ws + 48*MB);
  u16* VTp = (u16*)(ws + 56*MB);
  u16* AO  = (u16*)(ws + 64*MB);

  int n4 = M*D/4;  // 1048576 per tensor
  CvtArgs ca; ca.x[0]=query; ca.x[1]=key; ca.x[2]=value; ca.y[0]=xq; ca.y[1]=xk; ca.y[2]=xv;
  k_cvt3<<<dim3(n4/256, 3), 256, 0, stream>>>(ca, n4);

  TwbArgs ta; ta.W[0]=Wq; ta.W[1]=Wk; ta.W[2]=Wv; ta.W[3]=Wo;
  ta.Wt[0]=WqT; ta.Wt[1]=WkT; ta.Wt[2]=WvT; ta.Wt[3]=WoT;
  k_twb4<<<dim3(32,32,4), dim3(32,8), 0, stream>>>(ta);

  GemmArgs3 ga;
  ga.A[0]=xq; ga.A[1]=xk; ga.A[2]=xv;
  ga.Bt[0]=WqT; ga.Bt[1]=WkT; ga.Bt[2]=WvT;
  ga.bias[0]=bq; ga.bias[1]=bk; ga.bias[2]=bv;
  ga.C[0]=Qp; ga.C[1]=Kp; ga.C[2]=Vp;
  k_gemm3<<<dim3(32,8,3), 256, 0, stream>>>(ga);

  k_tv<<<dim3(T/32, 2, 32), dim3(32,8), 0, stream>>>(Vp, VTp);
  k_attn<<<dim3(16, 32), 256, 0, stream>>>(Qp, Kp, VTp, AO);
  k_gemmO<<<dim3(32,8), 256, 0, stream>>>(AO, WoT, bo, out);
}

// Round 4
// 132.294 us; speedup vs baseline: 2.6948x; 1.0703x over previous
//
#include <hip/hip_runtime.h>

typedef unsigned short u16;
typedef __attribute__((ext_vector_type(4))) float f32x4;
typedef __attribute__((ext_vector_type(8))) short bf16x8;

#define MFMA16(a,b,c) __builtin_amdgcn_mfma_f32_16x16x32_bf16((a),(b),(c),0,0,0)

__device__ inline u16 f2bf(float f){
  union { float f; unsigned u; } v; v.f = f;
  unsigned r = v.u + 0x7FFFu + ((v.u >> 16) & 1u);
  return (u16)(r >> 16);
}
__device__ inline u16 f2bf_fast(float f){
  union { float f; unsigned u; } v; v.f = f;
  return (u16)((v.u + 0x8000u) >> 16);
}
__device__ inline void storeC(float* p, float v){ *p = v; }
__device__ inline void storeC(u16* p, float v){ *p = f2bf(v); }

typedef const __attribute__((address_space(1))) unsigned int* gas_ptr;
typedef __attribute__((address_space(3))) unsigned int* las_ptr;
__device__ inline void gload_lds16(const u16* g, u16* l){
  __builtin_amdgcn_global_load_lds((gas_ptr)(const void*)g, (las_ptr)(void*)l, 16, 0, 0);
}

template<int N>
__device__ inline float rorf(float v){
  union { float f; int i; } a, b; a.f = v;
  b.i = __builtin_amdgcn_update_dpp(a.i, a.i, 0x120|N, 0xF, 0xF, false);
  return b.f;
}
__device__ inline float redMax16(float v){
  v = fmaxf(v, rorf<8>(v)); v = fmaxf(v, rorf<4>(v));
  v = fmaxf(v, rorf<2>(v)); v = fmaxf(v, rorf<1>(v));
  return v;
}

// ---------------- fp32 -> bf16 convert, 3 tensors in one launch ----------------
struct CvtArgs { const float* x[3]; u16* y[3]; };
__global__ void k_cvt3(CvtArgs a, int n4){
  const float* x = a.x[blockIdx.y];
  u16* y = a.y[blockIdx.y];
  int i = blockIdx.x*blockDim.x + threadIdx.x;
  if (i < n4){
    float4 v = ((const float4*)x)[i];
    ushort4 o;
    o.x = f2bf(v.x); o.y = f2bf(v.y); o.z = f2bf(v.z); o.w = f2bf(v.w);
    ((ushort4*)y)[i] = o;
  }
}

// ---------------- W (K x N) fp32 -> Wt (N x K) bf16, 4 weights ----------------
struct TwbArgs { const float* W[4]; u16* Wt[4]; };
__global__ void k_twb4(TwbArgs a){
  __shared__ u16 t[32][33];
  const float* W = a.W[blockIdx.z];
  u16* Wt = a.Wt[blockIdx.z];
  int kb = blockIdx.x*32, nb = blockIdx.y*32;
  int tx = threadIdx.x, ty = threadIdx.y;
  #pragma unroll
  for (int i=0;i<32;i+=8)
    t[ty+i][tx] = f2bf(W[(size_t)(kb+ty+i)*1024 + nb+tx]);
  __syncthreads();
  #pragma unroll
  for (int i=0;i<32;i+=8)
    Wt[(size_t)(nb+ty+i)*1024 + kb+tx] = t[tx][ty+i];
}

// ---------------- V (B*T, D) bf16 -> VT (B,H,DH,T) bf16 ----------------
__global__ void k_tv(const u16* __restrict__ V, u16* __restrict__ VT){
  __shared__ u16 t[32][33];
  int tb = blockIdx.x*32;
  int db = blockIdx.y*32;
  int bh = blockIdx.z;
  int b = bh>>4, h = bh&15;
  int tx = threadIdx.x, ty = threadIdx.y;
  #pragma unroll
  for (int i=0;i<32;i+=8)
    t[ty+i][tx] = V[(size_t)(b*2048 + tb+ty+i)*1024 + h*64 + db+tx];
  __syncthreads();
  #pragma unroll
  for (int i=0;i<32;i+=8)
    VT[(size_t)(bh*64 + db+ty+i)*2048 + tb+tx] = t[tx][ty+i];
}

// ---------------- bf16 GEMM body ----------------
template<typename OutT>
__device__ inline void gemm_body(const u16* __restrict__ A, const u16* __restrict__ Bt,
                                 const float* __restrict__ bias, OutT* __restrict__ C,
                                 int bx, int by){
  const int N=1024, K=1024;
  __shared__ __attribute__((aligned(16))) u16 As[128*64];
  __shared__ __attribute__((aligned(16))) u16 Bs[128*64];
  const int tid  = threadIdx.x;
  const int wave = tid>>6, lane = tid&63;
  const int lo = lane&15, hi = lane>>4;
  const int row0 = bx*128, col0 = by*128;
  const int wm = (wave>>1)*64, wn = (wave&1)*64;
  f32x4 acc[4][4];
  #pragma unroll
  for (int i=0;i<4;i++)
    #pragma unroll
    for (int j=0;j<4;j++) acc[i][j] = (f32x4){0.f,0.f,0.f,0.f};

  for (int k0=0; k0<K; k0+=64){
    #pragma unroll
    for (int r=0;r<4;r++){
      int c = r*256 + tid;
      gload_lds16(A  + (size_t)(row0 + (c>>3))*K + k0 + (c&7)*8, As + c*8);
      gload_lds16(Bt + (size_t)(col0 + (c>>3))*K + k0 + (c&7)*8, Bs + c*8);
    }
    __syncthreads();
    __builtin_amdgcn_s_setprio(1);
    #pragma unroll
    for (int ks=0;ks<2;ks++){
      bf16x8 af[4], bfr[4];
      #pragma unroll
      for (int mf=0;mf<4;mf++)
        af[mf] = *(const bf16x8*)(As + (wm+mf*16+lo)*64 + ks*32 + hi*8);
      #pragma unroll
      for (int nf=0;nf<4;nf++)
        bfr[nf] = *(const bf16x8*)(Bs + (wn+nf*16+lo)*64 + ks*32 + hi*8);
      #pragma unroll
      for (int mf=0;mf<4;mf++)
        #pragma unroll
        for (int nf=0;nf<4;nf++)
          acc[mf][nf] = MFMA16(af[mf], bfr[nf], acc[mf][nf]);
    }
    __builtin_amdgcn_s_setprio(0);
    __syncthreads();
  }
  #pragma unroll
  for (int mf=0;mf<4;mf++){
    #pragma unroll
    for (int nf=0;nf<4;nf++){
      int r0 = row0 + wm + mf*16 + hi*4;
      int c0 = col0 + wn + nf*16 + lo;
      float bb = bias[c0];
      #pragma unroll
      for (int r=0;r<4;r++)
        storeC(&C[(size_t)(r0+r)*N + c0], acc[mf][nf][r] + bb);
    }
  }
}

struct GemmArgs3 { const u16* A[3]; const u16* Bt[3]; const float* bias[3]; u16* C[3]; };
__global__ __launch_bounds__(256) void k_gemm3(GemmArgs3 g){
  int flat = blockIdx.x + (blockIdx.y<<5) + (blockIdx.z<<8);
  int swz = (flat&7)*96 + (flat>>3);
  int by = swz & 7, bx = (swz>>3) & 31, bz = swz >> 8;
  gemm_body<u16>(g.A[bz], g.Bt[bz], g.bias[bz], g.C[bz], bx, by);
}
__global__ __launch_bounds__(256) void k_gemmO(const u16* __restrict__ A, const u16* __restrict__ Bt,
                                               const float* __restrict__ bias, float* __restrict__ C){
  int flat = blockIdx.x + (blockIdx.y<<5);
  int swz = (flat&7)*32 + (flat>>3);
  int by = swz & 7, bx = swz >> 3;
  gemm_body<float>(A, Bt, bias, C, bx, by);
}

// ---------------- flash attention (causal), v4 ----------------
// grid (32,32) = 1024 blocks, one 64-row q-tile each; heavy-first (qb desc)
// dispatch for LPT balance; 4 bh per XCD for L2 KV locality. 4 blocks/CU.
__global__ __launch_bounds__(256) void k_attn(
    const u16* __restrict__ Q, const u16* __restrict__ Kp,
    const u16* __restrict__ VT, u16* __restrict__ O)
{
  const int T=2048, D=1024;
  __shared__ __attribute__((aligned(16))) u16 Ks[2][64*64];
  __shared__ __attribute__((aligned(16))) u16 Vs[2][64*64];
  __shared__ __attribute__((aligned(16))) u16 Plds[4][16*64];
  int f = blockIdx.x + (blockIdx.y<<5);
  int xcd = f & 7, idx = f >> 3;
  const int bh = (xcd<<2) | (idx&3);
  const int qb = 31 - (idx>>2);
  const int b = bh>>4, h = bh&15;
  const int tid = threadIdx.x;
  const int wave = tid>>6, lane = tid&63;
  const int lo = lane&15, hi = lane>>4;
  const float NEG = -__builtin_inff();
  const float sc = 0.125f * 1.44269504f;
  const bf16x8 ones = {0x3F80,0x3F80,0x3F80,0x3F80,0x3F80,0x3F80,0x3F80,0x3F80};

  const int cof0 = ((hi    ) ^ (lo&7))*8;
  const int cof1 = ((hi + 4) ^ (lo&7))*8;

  const int c0 = tid, c1 = 256 + tid;
  const int sr0 = c0>>3, sj0 = (c0&7)^(sr0&7);
  const int sr1 = c1>>3, sj1 = (c1&7)^(sr1&7);
  const u16* Kbase = Kp + (size_t)(b*T)*D + h*64;
  const u16* Vbase = VT + (size_t)(bh*64)*T;
  const size_t kOff0 = (size_t)sr0*D + sj0*8, kOff1 = (size_t)sr1*D + sj1*8;
  const size_t vOff0 = (size_t)sr0*T + sj0*8, vOff1 = (size_t)sr1*T + sj1*8;

  const int qrow0 = qb*64 + wave*16;
  const u16* Qb = Q + (size_t)(b*T + qrow0 + lo)*D + h*64;
  bf16x8 qf0 = *(const bf16x8*)(Qb + hi*8);
  bf16x8 qf1 = *(const bf16x8*)(Qb + 32 + hi*8);

  f32x4 o[4];
  #pragma unroll
  for (int nf=0;nf<4;nf++) o[nf] = (f32x4){0.f,0.f,0.f,0.f};
  float m[4], l[4];
  #pragma unroll
  for (int r=0;r<4;r++){ m[r] = NEG; l[r] = 0.f; }

  gload_lds16(Kbase + kOff0, &Ks[0][c0*8]);
  gload_lds16(Kbase + kOff1, &Ks[0][c1*8]);
  gload_lds16(Vbase + vOff0, &Vs[0][c0*8]);
  gload_lds16(Vbase + vOff1, &Vs[0][c1*8]);
  __syncthreads();

  int cur = 0;
  for (int kb=0; kb<=qb; kb++){
    if (kb < qb){
      const u16* Kt = Kbase + (size_t)(kb+1)*64*D;
      const u16* Vt = Vbase + (kb+1)*64;
      gload_lds16(Kt + kOff0, &Ks[cur^1][c0*8]);
      gload_lds16(Kt + kOff1, &Ks[cur^1][c1*8]);
      gload_lds16(Vt + vOff0, &Vs[cur^1][c0*8]);
      gload_lds16(Vt + vOff1, &Vs[cur^1][c1*8]);
    }
    const u16* Kl = Ks[cur];
    const u16* Vl = Vs[cur];
    // ---- S = Q K^T (raw units) ----
    f32x4 s[4];
    __builtin_amdgcn_s_setprio(1);
    #pragma unroll
    for (int nf=0;nf<4;nf++){
      int row = nf*16 + lo;
      bf16x8 kf0 = *(const bf16x8*)(Kl + row*64 + cof0);
      bf16x8 kf1 = *(const bf16x8*)(Kl + row*64 + cof1);
      f32x4 z = (f32x4){0.f,0.f,0.f,0.f};
      z = MFMA16(qf0, kf0, z);
      s[nf] = MFMA16(qf1, kf1, z);
    }
    __builtin_amdgcn_s_setprio(0);
    // ---- causal mask (diag only) + row max ----
    float pm[4] = {NEG,NEG,NEG,NEG};
    if (kb == qb){
      #pragma unroll
      for (int nf=0;nf<4;nf++){
        int col = kb*64 + nf*16 + lo;
        #pragma unroll
        for (int r=0;r<4;r++){
          int row = qrow0 + hi*4 + r;
          if (col > row) s[nf][r] = NEG;
          pm[r] = fmaxf(pm[r], s[nf][r]);
        }
      }
    } else {
      #pragma unroll
      for (int nf=0;nf<4;nf++)
        #pragma unroll
        for (int r=0;r<4;r++)
          pm[r] = fmaxf(pm[r], s[nf][r]);
    }
    #pragma unroll
    for (int r=0;r<4;r++) pm[r] = redMax16(pm[r]);
    // ---- defer-rescale: raw threshold 8/sc ~= 44 ----
    bool small = true;
    #pragma unroll
    for (int r=0;r<4;r++) small = small && (pm[r] <= m[r] + 44.f);
    const bool resc = !__all(small);
    float alpha[4];
    if (resc){
      #pragma unroll
      for (int r=0;r<4;r++){
        float mn = fmaxf(m[r], pm[r]);
        alpha[r] = __builtin_amdgcn_exp2f((m[r] - mn)*sc);
        m[r] = mn;
      }
      #pragma unroll
      for (int nf=0;nf<4;nf++)
        #pragma unroll
        for (int r=0;r<4;r++) o[nf][r] *= alpha[r];
    }
    float msc[4];
    #pragma unroll
    for (int r=0;r<4;r++) msc[r] = m[r]*sc;
    // ---- P = exp2(fma(s, sc, -m*sc)), store bf16 to LDS ----
    #pragma unroll
    for (int nf=0;nf<4;nf++)
      #pragma unroll
      for (int r=0;r<4;r++){
        float p = __builtin_amdgcn_exp2f(__builtin_fmaf(s[nf][r], sc, -msc[r]));
        int prow = hi*4+r, pcol = nf*16+lo;
        Plds[wave][prow*64 + (pcol ^ ((prow&7)<<3))] = f2bf_fast(p);
      }
    // ---- O += P V ; l rowsum via ones-MFMA ----
    bf16x8 pa0 = *(const bf16x8*)(&Plds[wave][lo*64 + cof0]);
    bf16x8 pa1 = *(const bf16x8*)(&Plds[wave][lo*64 + cof1]);
    f32x4 lsum = (f32x4){0.f,0.f,0.f,0.f};
    __builtin_amdgcn_s_setprio(1);
    lsum = MFMA16(pa0, ones, lsum);
    lsum = MFMA16(pa1, ones, lsum);
    #pragma unroll
    for (int nf=0;nf<4;nf++){
      int row = nf*16 + lo;
      bf16x8 v0 = *(const bf16x8*)(Vl + row*64 + cof0);
      bf16x8 v1 = *(const bf16x8*)(Vl + row*64 + cof1);
      o[nf] = MFMA16(pa0, v0, o[nf]);
      o[nf] = MFMA16(pa1, v1, o[nf]);
    }
    __builtin_amdgcn_s_setprio(0);
    if (resc){
      #pragma unroll
      for (int r=0;r<4;r++) l[r] = l[r]*alpha[r] + lsum[r];
    } else {
      #pragma unroll
      for (int r=0;r<4;r++) l[r] += lsum[r];
    }
    __syncthreads();
    cur ^= 1;
  }
  #pragma unroll
  for (int nf=0;nf<4;nf++)
    #pragma unroll
    for (int r=0;r<4;r++){
      int row = qrow0 + hi*4 + r;
      O[(size_t)(b*T+row)*D + h*64 + nf*16 + lo] = f2bf_fast(o[nf][r] / l[r]);
    }
}

extern "C" void kernel_launch(void* const* d_in, const int* in_sizes, int n_in,
                              void* d_out, int out_size, void* d_ws, size_t ws_size,
                              hipStream_t stream) {
  const int B=2, T=2048, D=1024;
  const int M = B*T;
  const float* query = (const float*)d_in[0];
  const float* key   = (const float*)d_in[1];
  const float* value = (const float*)d_in[2];
  const float* Wq = (const float*)d_in[3];  const float* bq = (const float*)d_in[4];
  const float* Wk = (const float*)d_in[5];  const float* bk = (const float*)d_in[6];
  const float* Wv = (const float*)d_in[7];  const float* bv = (const float*)d_in[8];
  const float* Wo = (const float*)d_in[9];  const float* bo = (const float*)d_in[10];
  float* out = (float*)d_out;

  char* ws = (char*)d_ws;
  const size_t MB = 1024*1024;
  u16* xq  = (u16*)(ws + 0*MB);
  u16* xk  = (u16*)(ws + 8*MB);
  u16* xv  = (u16*)(ws + 16*MB);
  u16* WqT = (u16*)(ws + 24*MB);
  u16* WkT = (u16*)(ws + 26*MB);
  u16* WvT = (u16*)(ws + 28*MB);
  u16* WoT = (u16*)(ws + 30*MB);
  u16* Qp  = (u16*)(ws + 32*MB);
  u16* Kp  = (u16*)(ws + 40*MB);
  u16* Vp  = (u16*)(ws + 48*MB);
  u16* VTp = (u16*)(ws + 56*MB);
  u16* AO  = (u16*)(ws + 64*MB);

  int n4 = M*D/4;
  CvtArgs ca; ca.x[0]=query; ca.x[1]=key; ca.x[2]=value; ca.y[0]=xq; ca.y[1]=xk; ca.y[2]=xv;
  k_cvt3<<<dim3(n4/256, 3), 256, 0, stream>>>(ca, n4);

  TwbArgs ta; ta.W[0]=Wq; ta.W[1]=Wk; ta.W[2]=Wv; ta.W[3]=Wo;
  ta.Wt[0]=WqT; ta.Wt[1]=WkT; ta.Wt[2]=WvT; ta.Wt[3]=WoT;
  k_twb4<<<dim3(32,32,4), dim3(32,8), 0, stream>>>(ta);

  GemmArgs3 ga;
  ga.A[0]=xq; ga.A[1]=xk; ga.A[2]=xv;
  ga.Bt[0]=WqT; ga.Bt[1]=WkT; ga.Bt[2]=WvT;
  ga.bias[0]=bq; ga.bias[1]=bk; ga.bias[2]=bv;
  ga.C[0]=Qp; ga.C[1]=Kp; ga.C[2]=Vp;
  k_gemm3<<<dim3(32,8,3), 256, 0, stream>>>(ga);

  k_tv<<<dim3(T/32, 2, 32), dim3(32,8), 0, stream>>>(Vp, VTp);
  k_attn<<<dim3(32,32), 256, 0, stream>>>(Qp, Kp, VTp, AO);
  k_gemmO<<<dim3(32,8), 256, 0, stream>>>(AO, WoT, bo, out);
}